// Round 2
// baseline (163.370 us; speedup 1.0000x reference)
//
#include <hip/hip_runtime.h>
#include <hip/hip_bf16.h>

#define NQ 12
typedef __hip_bfloat16 bf16;
typedef float v2f __attribute__((ext_vector_type(2)));

__device__ __forceinline__ float b2f(unsigned int u) {
  union { unsigned int i; float f; } v; v.i = u << 16; return v.f;
}

// Dtype-adaptive scalar load (world: f32 — probe-verified on HW R5..R16).
__device__ __forceinline__ float ldv(const void* p, int i, bool f32) {
  if (f32) return ((const float*)p)[i];
  return b2f((unsigned int)((const unsigned short*)p)[i]);
}

// Composite permutation of the 12 sequential ring CNOTs. HW-verified (R2..R16).
// Linear over GF(2) — exploited by the phase-split transposes below.
__device__ __forceinline__ int ringperm(int d) {
  int a = d ^ ((d & 1) << 11);
  return a ^ (a >> 1);
}

// LDS bank swizzle. HW-verified conflict-free (SQ_LDS_BANK_CONFLICT=0, R7..R16).
__device__ __forceinline__ int swz(int p) { return p ^ ((p >> 6) & 31); }

// One wave per batch element; state in 32 packed float2 regs (64 amps/lane).
// R17: occupancy attack. R16 profile: VALUBusy 18.8%, VGPR 164 (-> 2 waves/SIMD
// per m69 stepping), LDS 16KiB (-> 10 blocks/CU). Kernel is latency-bound.
// Changes vs proven R16/84.1us structure:
//  (1) REVERT Walsh Z-tree (R1 regression) -> flat Z loop restored verbatim.
//  (2) LDS 16KiB -> 8KiB: each 64x64 transpose split into two 2048-float
//      phases along a GF(2) invariant of its permutation (pure transpose:
//      tag j5^lane5 = addr bit5^bit11; ring-perm transpose: tag j4^j5^lane4
//      = addr bit4^bit11). Bit11 is redundant within a phase -> compressed
//      address = full_addr & 2047. Per-lane read/write register sets are
//      phase-closed -> no clobber, no temps, bit-exact.
//  (3) VGPR -> <=128 via __launch_bounds__(64,4) + fused init cos/sin and
//      q-outer head loop (no ct/sn arrays).
// Target: 16 blocks/CU resident (grid is exactly 16/CU), 4 waves/SIMD.
__global__ __launch_bounds__(64, 4) void qsim_kernel(
    const void* __restrict__ x,    // [B,12] f32
    const void* __restrict__ w,    // [2,12] f32
    const void* __restrict__ Wm,   // [2,12] f32
    const void* __restrict__ bv,   // [2]    f32
    void* __restrict__ out)        // [B,2]  f32
{
  __shared__ float st[2048];       // 8 KiB (was 16 KiB)
  const int lane = threadIdx.x;
  const int b = blockIdx.x;

  // ---- inline dtype probe (HW-proven R5..R16) ----
  bool f32;
  {
    const unsigned short* xu = (const unsigned short*)x;
    int insane = 0;
#pragma unroll
    for (int i = 0; i < 16; ++i) {
      float v = b2f((unsigned int)xu[2 * i]);
      float a = fabsf(v);
      if (!(a <= 64.f) || (a != 0.f && a < 1e-8f)) ++insane;
    }
    f32 = (insane >= 2);
  }

  // ---- direct init in layout B (layer-1 CNOT perm folded, no LDS) ----
  // cos/sin fused into f0/f1 (no csx/snx arrays -> lower VGPR peak).
  v2f amp[32];
  {
    const int rb = ringperm(lane << 6);
    float f0[12], f1[12];
#pragma unroll
    for (int q = 0; q < 12; ++q) {
      float h = 0.5f * ldv(x, b * NQ + q, f32);
      float c = __cosf(h), s = __sinf(h);
      int r = (rb >> (11 - q)) & 1;
      f0[q] = r ? s : c;
      f1[q] = r ? c : s;
    }
    const float K   = f0[2] * f0[3] * f0[4] * f0[5];
    const float h0f = f0[0] * f0[1];
    const float h1f = f1[0] * f1[1];
    const float u00 = f0[11] * h0f, u01 = f1[11] * h1f;
    const float u10 = f1[11] * h0f, u11 = f0[11] * h1f;
#pragma unroll
    for (int j5 = 0; j5 < 2; ++j5) {
      const float a5 = K * (j5 ? f1[6] : f0[6]);
#pragma unroll
      for (int j4 = 0; j4 < 2; ++j4) {
        const float a4 = a5 * ((j4 ^ j5) ? f1[7] : f0[7]);
#pragma unroll
        for (int j3 = 0; j3 < 2; ++j3) {
          const float a3 = a4 * ((j3 ^ j4) ? f1[8] : f0[8]);
#pragma unroll
          for (int j2 = 0; j2 < 2; ++j2) {
            const float a2 = a3 * ((j2 ^ j3) ? f1[9] : f0[9]);
#pragma unroll
            for (int j1 = 0; j1 < 2; ++j1) {
              const float a1 = a2 * ((j1 ^ j2) ? f1[10] : f0[10]);
              const int k = (j5 << 4) | (j4 << 3) | (j3 << 2) | (j2 << 1) | j1;
              amp[k].x = a1 * (j1 ? u10 : u00);
              amp[k].y = a1 * (j1 ? u11 : u01);
            }
          }
        }
      }
    }
  }

  const int rb1 = swz(ringperm(lane << 6));      // layer-2 pass-1 read base

  // ================= layer 1: RY gates (3-shear form; R15/R16) =============
#pragma unroll
  for (int q = 6; q < 11; ++q) {
    float h = 0.5f * ldv(w, 0 * NQ + q, f32);
    const float t = __tanf(0.5f * h), s = __sinf(h);
    const int hm = 1 << (10 - q);
#pragma unroll
    for (int k = 0; k < 32; ++k) {
      if (k & hm) continue;
      amp[k]      += -t * amp[k | hm];
      amp[k | hm] +=  s * amp[k];
      amp[k]      += -t * amp[k | hm];
    }
  }
  {
    float h = 0.5f * ldv(w, 0 * NQ + 11, f32);
    const float t = __tanf(0.5f * h), s = __sinf(h);
#pragma unroll
    for (int k = 0; k < 32; ++k) {
      amp[k].x = fmaf(-t, amp[k].y, amp[k].x);
      amp[k].y = fmaf( s, amp[k].x, amp[k].y);
      amp[k].x = fmaf(-t, amp[k].y, amp[k].x);
    }
  }

  // ---- T1: pure transpose B -> A, 8KiB two-phase split ----
  // Phase tag = j5 ^ lane5 (same-half first, cross-half second).
  __syncthreads();
  if (lane < 32) {
#pragma unroll
    for (int j = 0; j < 32; ++j)
      st[((lane << 6) ^ (lane & 31) ^ j) & 2047] = amp[j >> 1][j & 1];
  } else {
#pragma unroll
    for (int j = 32; j < 64; ++j)
      st[((lane << 6) ^ (lane & 31) ^ j) & 2047] = amp[j >> 1][j & 1];
  }
  __syncthreads();
  if (lane < 32) {
#pragma unroll
    for (int j = 0; j < 32; ++j)
      amp[j >> 1][j & 1] = st[(((j << 6) ^ (j & 31)) ^ lane) & 2047];
  } else {
#pragma unroll
    for (int j = 32; j < 64; ++j)
      amp[j >> 1][j & 1] = st[(((j << 6) ^ (j & 31)) ^ lane) & 2047];
  }
  __syncthreads();
  if (lane < 32) {
#pragma unroll
    for (int j = 32; j < 64; ++j)
      st[((lane << 6) ^ (lane & 31) ^ j) & 2047] = amp[j >> 1][j & 1];
  } else {
#pragma unroll
    for (int j = 0; j < 32; ++j)
      st[((lane << 6) ^ (lane & 31) ^ j) & 2047] = amp[j >> 1][j & 1];
  }
  __syncthreads();
  if (lane < 32) {
#pragma unroll
    for (int j = 32; j < 64; ++j)
      amp[j >> 1][j & 1] = st[(((j << 6) ^ (j & 31)) ^ lane) & 2047];
  } else {
#pragma unroll
    for (int j = 0; j < 32; ++j)
      amp[j >> 1][j & 1] = st[(((j << 6) ^ (j & 31)) ^ lane) & 2047];
  }

  // ---- q0..4 packed (layout A), q5 in-element (R15/R16) ----
#pragma unroll
  for (int q = 0; q < 5; ++q) {
    float h = 0.5f * ldv(w, 0 * NQ + q, f32);
    const float t = __tanf(0.5f * h), s = __sinf(h);
    const int hm = 1 << (4 - q);
#pragma unroll
    for (int k = 0; k < 32; ++k) {
      if (k & hm) continue;
      amp[k]      += -t * amp[k | hm];
      amp[k | hm] +=  s * amp[k];
      amp[k]      += -t * amp[k | hm];
    }
  }
  {
    float h = 0.5f * ldv(w, 0 * NQ + 5, f32);
    const float t = __tanf(0.5f * h), s = __sinf(h);
#pragma unroll
    for (int k = 0; k < 32; ++k) {
      amp[k].x = fmaf(-t, amp[k].y, amp[k].x);
      amp[k].y = fmaf( s, amp[k].x, amp[k].y);
      amp[k].x = fmaf(-t, amp[k].y, amp[k].x);
    }
  }

  // ================= layer 2: CNOT perm only; RYs folded ===================
  // ---- T2: ring-CNOT perm + transpose A -> B, 8KiB two-phase split ----
  // Invariant functional: tag = j4 ^ j5 ^ lane4 (= addr bit4 ^ bit11).
  // Phase A j-sets: lane4==0 -> {0..15,48..63}; lane4==1 -> {16..47}.
  __syncthreads();
  if ((lane & 16) == 0) {
#pragma unroll
    for (int j = 0; j < 64; ++j) {
      if (((j >> 4) ^ (j >> 5)) & 1) continue;
      st[((((j << 6) ^ (j & 31)) ^ lane)) & 2047] = amp[j >> 1][j & 1];
    }
  } else {
#pragma unroll
    for (int j = 16; j < 48; ++j)
      st[((((j << 6) ^ (j & 31)) ^ lane)) & 2047] = amp[j >> 1][j & 1];
  }
  __syncthreads();
  if ((lane & 16) == 0) {
#pragma unroll
    for (int j = 0; j < 64; ++j) {
      if (((j >> 4) ^ (j >> 5)) & 1) continue;
      amp[j >> 1][j & 1] = st[(rb1 ^ swz(ringperm(j))) & 2047];
    }
  } else {
#pragma unroll
    for (int j = 16; j < 48; ++j)
      amp[j >> 1][j & 1] = st[(rb1 ^ swz(ringperm(j))) & 2047];
  }
  __syncthreads();
  if ((lane & 16) == 0) {
#pragma unroll
    for (int j = 16; j < 48; ++j)
      st[((((j << 6) ^ (j & 31)) ^ lane)) & 2047] = amp[j >> 1][j & 1];
  } else {
#pragma unroll
    for (int j = 0; j < 64; ++j) {
      if (((j >> 4) ^ (j >> 5)) & 1) continue;
      st[((((j << 6) ^ (j & 31)) ^ lane)) & 2047] = amp[j >> 1][j & 1];
    }
  }
  __syncthreads();
  if ((lane & 16) == 0) {
#pragma unroll
    for (int j = 16; j < 48; ++j)
      amp[j >> 1][j & 1] = st[(rb1 ^ swz(ringperm(j))) & 2047];
  } else {
#pragma unroll
    for (int j = 0; j < 64; ++j) {
      if (((j >> 4) ^ (j >> 5)) & 1) continue;
      amp[j >> 1][j & 1] = st[(rb1 ^ swz(ringperm(j))) & 2047];
    }
  }

  // ---- <X_q> partials, q6..11 (register-local in B; halved pairs; R16) ----
  float xB6, xB7, xB8, xB9, xB10, xB11;
  {
    v2f a6 = {0.f, 0.f}, a7 = a6, a8 = a6, a9 = a6, a10 = a6;
    float a11 = 0.f;
#pragma unroll
    for (int k = 0; k < 32; ++k) {
      if (!(k & 16)) a6  += amp[k] * amp[k | 16];
      if (!(k & 8))  a7  += amp[k] * amp[k | 8];
      if (!(k & 4))  a8  += amp[k] * amp[k | 4];
      if (!(k & 2))  a9  += amp[k] * amp[k | 2];
      if (!(k & 1))  a10 += amp[k] * amp[k | 1];
      a11 += amp[k].x * amp[k].y;
    }
    xB6 = 2.f * (a6.x + a6.y);  xB7 = 2.f * (a7.x + a7.y);
    xB8 = 2.f * (a8.x + a8.y);  xB9 = 2.f * (a9.x + a9.y);
    xB10 = 2.f * (a10.x + a10.y); xB11 = 2.f * a11;
  }

  // ---- T3: pure transpose B -> A, 8KiB two-phase split (same as T1) ----
  __syncthreads();
  if (lane < 32) {
#pragma unroll
    for (int j = 0; j < 32; ++j)
      st[((lane << 6) ^ (lane & 31) ^ j) & 2047] = amp[j >> 1][j & 1];
  } else {
#pragma unroll
    for (int j = 32; j < 64; ++j)
      st[((lane << 6) ^ (lane & 31) ^ j) & 2047] = amp[j >> 1][j & 1];
  }
  __syncthreads();
  if (lane < 32) {
#pragma unroll
    for (int j = 0; j < 32; ++j)
      amp[j >> 1][j & 1] = st[(((j << 6) ^ (j & 31)) ^ lane) & 2047];
  } else {
#pragma unroll
    for (int j = 32; j < 64; ++j)
      amp[j >> 1][j & 1] = st[(((j << 6) ^ (j & 31)) ^ lane) & 2047];
  }
  __syncthreads();
  if (lane < 32) {
#pragma unroll
    for (int j = 32; j < 64; ++j)
      st[((lane << 6) ^ (lane & 31) ^ j) & 2047] = amp[j >> 1][j & 1];
  } else {
#pragma unroll
    for (int j = 0; j < 32; ++j)
      st[((lane << 6) ^ (lane & 31) ^ j) & 2047] = amp[j >> 1][j & 1];
  }
  __syncthreads();
  if (lane < 32) {
#pragma unroll
    for (int j = 32; j < 64; ++j)
      amp[j >> 1][j & 1] = st[(((j << 6) ^ (j & 31)) ^ lane) & 2047];
  } else {
#pragma unroll
    for (int j = 0; j < 32; ++j)
      amp[j >> 1][j & 1] = st[(((j << 6) ^ (j & 31)) ^ lane) & 2047];
  }

  // ---- <X_q> partials, q0..5 (register-local in A; halved pairs; R16) ----
  float xA0, xA1, xA2, xA3, xA4, xA5;
  {
    v2f a0 = {0.f, 0.f}, a1 = a0, a2 = a0, a3 = a0, a4 = a0;
    float a5 = 0.f;
#pragma unroll
    for (int k = 0; k < 32; ++k) {
      if (!(k & 16)) a0 += amp[k] * amp[k | 16];
      if (!(k & 8))  a1 += amp[k] * amp[k | 8];
      if (!(k & 4))  a2 += amp[k] * amp[k | 4];
      if (!(k & 2))  a3 += amp[k] * amp[k | 2];
      if (!(k & 1))  a4 += amp[k] * amp[k | 1];
      a5 += amp[k].x * amp[k].y;
    }
    xA0 = 2.f * (a0.x + a0.y);  xA1 = 2.f * (a1.x + a1.y);
    xA2 = 2.f * (a2.x + a2.y);  xA3 = 2.f * (a3.x + a3.y);
    xA4 = 2.f * (a4.x + a4.y);  xA5 = 2.f * a5;
  }

  // ---- <Z_q> partials (REVERTED to proven R16 flat loop, layout A) ----
  v2f Pv = {0.f, 0.f}, zv0 = Pv, zv1 = Pv, zv2 = Pv, zv3 = Pv, zv4 = Pv;
  float z5 = 0.f;
#pragma unroll
  for (int k = 0; k < 32; ++k) {
    v2f pr = amp[k] * amp[k];
    Pv += pr;
    zv0 += (k & 16) ? -pr : pr;
    zv1 += (k & 8)  ? -pr : pr;
    zv2 += (k & 4)  ? -pr : pr;
    zv3 += (k & 2)  ? -pr : pr;
    zv4 += (k & 1)  ? -pr : pr;
    z5  += pr.x - pr.y;
  }
  const float P  = Pv.x + Pv.y;
  const float z0 = zv0.x + zv0.y, z1 = zv1.x + zv1.y, z2 = zv2.x + zv2.y;
  const float z3 = zv3.x + zv3.y, z4 = zv4.x + zv4.y;

  const float zA[6] = {z0, z1, z2, z3, z4, z5};
  const float xA[6] = {xA0, xA1, xA2, xA3, xA4, xA5};
  const float xB[6] = {xB6, xB7, xB8, xB9, xB10, xB11};

  // ---- fused linear head, q-outer (no ct/sn arrays; math-identical) ----
  // <Z>_final = ct*Z - st*X per qubit, full layer-2 angle.
  float t0 = 0.f, t1 = 0.f, ws0 = 0.f, ws1 = 0.f;
#pragma unroll
  for (int q = 0; q < 12; ++q) {
    const float th = ldv(w, NQ + q, f32);
    const float c = __cosf(th), s = __sinf(th);
    const float w0 = ldv(Wm, q, f32);
    const float w1 = ldv(Wm, NQ + q, f32);
    if (q < 6) {
      const float zx = fmaf(c, zA[q], -s * xA[q]);
      t0 = fmaf(w0, zx, t0);
      t1 = fmaf(w1, zx, t1);
    } else {
      const float sx = -s * xB[q - 6];
      t0 = fmaf(w0, sx, t0);
      t1 = fmaf(w1, sx, t1);
      const float c0 = w0 * c, c1 = w1 * c;
      const bool neg = (lane >> (11 - q)) & 1;
      ws0 += neg ? -c0 : c0;
      ws1 += neg ? -c1 : c1;
    }
  }
  t0 = fmaf(P, ws0, t0);
  t1 = fmaf(P, ws1, t1);

#pragma unroll
  for (int off = 32; off; off >>= 1) {
    t0 += __shfl_xor(t0, off, 64);
    t1 += __shfl_xor(t1, off, 64);
  }
  if (lane < 2) {
    float o = ((lane == 0) ? t0 : t1) + ldv(bv, lane, f32);
    if (f32) ((float*)out)[b * 2 + lane] = o;
    else     ((bf16*)out)[b * 2 + lane] = __float2bfloat16(o);
  }
}

extern "C" void kernel_launch(void* const* d_in, const int* in_sizes, int n_in,
                              void* d_out, int out_size, void* d_ws, size_t ws_size,
                              hipStream_t stream) {
  const void* x  = d_in[0];
  const void* w  = d_in[1];
  const void* Wm = d_in[2];
  const void* bv = d_in[3];
  const int batch = out_size / 2;   // out is [B, 2]
  qsim_kernel<<<dim3(batch), dim3(64), 0, stream>>>(x, w, Wm, bv, d_out);
}

// Round 3
// 82.716 us; speedup vs baseline: 1.9751x; 1.9751x over previous
//
#include <hip/hip_runtime.h>
#include <hip/hip_bf16.h>

#define NQ 12
typedef __hip_bfloat16 bf16;
typedef float v2f __attribute__((ext_vector_type(2)));

__device__ __forceinline__ float b2f(unsigned int u) {
  union { unsigned int i; float f; } v; v.i = u << 16; return v.f;
}

// Dtype-adaptive scalar load (world: f32 — probe-verified on HW R5..R16).
__device__ __forceinline__ float ldv(const void* p, int i, bool f32) {
  if (f32) return ((const float*)p)[i];
  return b2f((unsigned int)((const unsigned short*)p)[i]);
}

// Composite permutation of the 12 sequential ring CNOTs. HW-verified (R2..R16).
__device__ __forceinline__ int ringperm(int d) {
  int a = d ^ ((d & 1) << 11);
  return a ^ (a >> 1);
}

// LDS bank swizzle (T2 only now). HW-verified conflict-free (R7..R16).
__device__ __forceinline__ int swz(int p) { return p ^ ((p >> 6) & 31); }

// One wave per batch element; state in 32 packed float2 regs (64 amps/lane).
// R18 = proven R16 structure (84.1us; VGPR 164, conflicts 0) with ONE change:
// the two PURE transposes (T1, T3) switch from the XOR-swizzled layout to a
// stride-65 PADDED layout. XOR costs 1 v_xor per DS op (not foldable into the
// additive ds imm offset); padding makes both sides additive:
//   write addr = lane*65 + j  -> base VGPR + imm offset, pairs -> ds_write2_b32
//   read  addr = j*65 + lane  -> base VGPR + imm offset (j*260 <= 16380 bytes)
// Banks: write (lane+j)%32, read (j+lane)%32 -> exactly 2 lanes/bank = free
// (m136). T1+T3: 512 -> ~200 instrs, all on the serial critical path.
// T2 (ring-perm transpose) keeps the proven XOR form. LDS 16384 -> 16640 B.
// R2 lesson: NO launch_bounds VGPR forcing (64-VGPR cap spilled amp[] ->
// 263 MB scratch traffic -> 106us). R1 lesson: no long-dep-chain trees.
__global__ __launch_bounds__(64) void qsim_kernel(
    const void* __restrict__ x,    // [B,12] f32
    const void* __restrict__ w,    // [2,12] f32
    const void* __restrict__ Wm,   // [2,12] f32
    const void* __restrict__ bv,   // [2]    f32
    void* __restrict__ out)        // [B,2]  f32
{
  __shared__ float st[4160];       // 64 rows x stride 65 (T1/T3); T2 uses <4096
  const int lane = threadIdx.x;
  const int b = blockIdx.x;

  // ---- inline dtype probe (HW-proven R5..R16) ----
  bool f32;
  {
    const unsigned short* xu = (const unsigned short*)x;
    int insane = 0;
#pragma unroll
    for (int i = 0; i < 16; ++i) {
      float v = b2f((unsigned int)xu[2 * i]);
      float a = fabsf(v);
      if (!(a <= 64.f) || (a != 0.f && a < 1e-8f)) ++insane;
    }
    f32 = (insane >= 2);
  }

  // ---- direct init in layout B (layer-1 CNOT perm folded, no LDS; R13..R16) ----
  v2f amp[32];
  {
    float csx[12], snx[12];
#pragma unroll
    for (int q = 0; q < 12; ++q) {
      float h = 0.5f * ldv(x, b * NQ + q, f32);
      csx[q] = __cosf(h); snx[q] = __sinf(h);
    }
    const int rb = ringperm(lane << 6);
    float f0[12], f1[12];
#pragma unroll
    for (int q = 0; q < 12; ++q) {
      int r = (rb >> (11 - q)) & 1;
      f0[q] = r ? snx[q] : csx[q];
      f1[q] = r ? csx[q] : snx[q];
    }
    const float K   = f0[2] * f0[3] * f0[4] * f0[5];
    const float h0f = f0[0] * f0[1];
    const float h1f = f1[0] * f1[1];
    const float u00 = f0[11] * h0f, u01 = f1[11] * h1f;
    const float u10 = f1[11] * h0f, u11 = f0[11] * h1f;
#pragma unroll
    for (int j5 = 0; j5 < 2; ++j5) {
      const float a5 = K * (j5 ? f1[6] : f0[6]);
#pragma unroll
      for (int j4 = 0; j4 < 2; ++j4) {
        const float a4 = a5 * ((j4 ^ j5) ? f1[7] : f0[7]);
#pragma unroll
        for (int j3 = 0; j3 < 2; ++j3) {
          const float a3 = a4 * ((j3 ^ j4) ? f1[8] : f0[8]);
#pragma unroll
          for (int j2 = 0; j2 < 2; ++j2) {
            const float a2 = a3 * ((j2 ^ j3) ? f1[9] : f0[9]);
#pragma unroll
            for (int j1 = 0; j1 < 2; ++j1) {
              const float a1 = a2 * ((j1 ^ j2) ? f1[10] : f0[10]);
              const int k = (j5 << 4) | (j4 << 3) | (j3 << 2) | (j2 << 1) | j1;
              amp[k].x = a1 * (j1 ? u10 : u00);
              amp[k].y = a1 * (j1 ? u11 : u01);
            }
          }
        }
      }
    }
  }

  const int rb1 = swz(ringperm(lane << 6));      // layer-2 pass-1 read base (T2)
  const int wpad = lane * 65;                    // padded write base (T1/T3)

  // ================= layer 1: RY gates (3-shear form; R15/R16) =============
#pragma unroll
  for (int q = 6; q < 11; ++q) {
    float h = 0.5f * ldv(w, 0 * NQ + q, f32);
    const float t = __tanf(0.5f * h), s = __sinf(h);
    const int hm = 1 << (10 - q);
#pragma unroll
    for (int k = 0; k < 32; ++k) {
      if (k & hm) continue;
      amp[k]      += -t * amp[k | hm];
      amp[k | hm] +=  s * amp[k];
      amp[k]      += -t * amp[k | hm];
    }
  }
  {
    float h = 0.5f * ldv(w, 0 * NQ + 11, f32);
    const float t = __tanf(0.5f * h), s = __sinf(h);
#pragma unroll
    for (int k = 0; k < 32; ++k) {
      amp[k].x = fmaf(-t, amp[k].y, amp[k].x);
      amp[k].y = fmaf( s, amp[k].x, amp[k].y);
      amp[k].x = fmaf(-t, amp[k].y, amp[k].x);
    }
  }

  // ---- T1: pure transpose B -> A, padded stride-65 (NEW: additive offsets) ----
  __syncthreads();
#pragma unroll
  for (int j = 0; j < 64; ++j)
    st[wpad + j] = amp[j >> 1][j & 1];
  __syncthreads();
#pragma unroll
  for (int j = 0; j < 64; ++j)
    amp[j >> 1][j & 1] = st[j * 65 + lane];

  // ---- q0..4 packed (layout A), q5 in-element (R15/R16) ----
#pragma unroll
  for (int q = 0; q < 5; ++q) {
    float h = 0.5f * ldv(w, 0 * NQ + q, f32);
    const float t = __tanf(0.5f * h), s = __sinf(h);
    const int hm = 1 << (4 - q);
#pragma unroll
    for (int k = 0; k < 32; ++k) {
      if (k & hm) continue;
      amp[k]      += -t * amp[k | hm];
      amp[k | hm] +=  s * amp[k];
      amp[k]      += -t * amp[k | hm];
    }
  }
  {
    float h = 0.5f * ldv(w, 0 * NQ + 5, f32);
    const float t = __tanf(0.5f * h), s = __sinf(h);
#pragma unroll
    for (int k = 0; k < 32; ++k) {
      amp[k].x = fmaf(-t, amp[k].y, amp[k].x);
      amp[k].y = fmaf( s, amp[k].x, amp[k].y);
      amp[k].x = fmaf(-t, amp[k].y, amp[k].x);
    }
  }

  // ================= layer 2: CNOT perm only; RYs folded (R15/R16) =========
  // ---- T2: ring-CNOT perm + transpose A -> B (XOR layout, R16-verbatim) ----
  __syncthreads();
#pragma unroll
  for (int j = 0; j < 64; ++j)
    st[((j << 6) ^ (j & 31)) ^ lane] = amp[j >> 1][j & 1];
  __syncthreads();
#pragma unroll
  for (int j = 0; j < 64; ++j)
    amp[j >> 1][j & 1] = st[rb1 ^ swz(ringperm(j))];

  // ---- <X_q> partials, q6..11 (register-local in B; halved pairs; R16) ----
  float xB6, xB7, xB8, xB9, xB10, xB11;
  {
    v2f a6 = {0.f, 0.f}, a7 = a6, a8 = a6, a9 = a6, a10 = a6;
    float a11 = 0.f;
#pragma unroll
    for (int k = 0; k < 32; ++k) {
      if (!(k & 16)) a6  += amp[k] * amp[k | 16];
      if (!(k & 8))  a7  += amp[k] * amp[k | 8];
      if (!(k & 4))  a8  += amp[k] * amp[k | 4];
      if (!(k & 2))  a9  += amp[k] * amp[k | 2];
      if (!(k & 1))  a10 += amp[k] * amp[k | 1];
      a11 += amp[k].x * amp[k].y;
    }
    xB6 = 2.f * (a6.x + a6.y);  xB7 = 2.f * (a7.x + a7.y);
    xB8 = 2.f * (a8.x + a8.y);  xB9 = 2.f * (a9.x + a9.y);
    xB10 = 2.f * (a10.x + a10.y); xB11 = 2.f * a11;
  }

  // ---- T3: pure transpose B -> A, padded stride-65 (NEW: additive offsets) ----
  __syncthreads();
#pragma unroll
  for (int j = 0; j < 64; ++j)
    st[wpad + j] = amp[j >> 1][j & 1];
  __syncthreads();
#pragma unroll
  for (int j = 0; j < 64; ++j)
    amp[j >> 1][j & 1] = st[j * 65 + lane];

  // ---- <X_q> partials, q0..5 (register-local in A; halved pairs; R16) ----
  float xA0, xA1, xA2, xA3, xA4, xA5;
  {
    v2f a0 = {0.f, 0.f}, a1 = a0, a2 = a0, a3 = a0, a4 = a0;
    float a5 = 0.f;
#pragma unroll
    for (int k = 0; k < 32; ++k) {
      if (!(k & 16)) a0 += amp[k] * amp[k | 16];
      if (!(k & 8))  a1 += amp[k] * amp[k | 8];
      if (!(k & 4))  a2 += amp[k] * amp[k | 4];
      if (!(k & 2))  a3 += amp[k] * amp[k | 2];
      if (!(k & 1))  a4 += amp[k] * amp[k | 1];
      a5 += amp[k].x * amp[k].y;
    }
    xA0 = 2.f * (a0.x + a0.y);  xA1 = 2.f * (a1.x + a1.y);
    xA2 = 2.f * (a2.x + a2.y);  xA3 = 2.f * (a3.x + a3.y);
    xA4 = 2.f * (a4.x + a4.y);  xA5 = 2.f * a5;
  }

  // ---- <Z_q> partials (R16-verbatim flat loop, layout A) ----
  v2f Pv = {0.f, 0.f}, zv0 = Pv, zv1 = Pv, zv2 = Pv, zv3 = Pv, zv4 = Pv;
  float z5 = 0.f;
#pragma unroll
  for (int k = 0; k < 32; ++k) {
    v2f pr = amp[k] * amp[k];
    Pv += pr;
    zv0 += (k & 16) ? -pr : pr;
    zv1 += (k & 8)  ? -pr : pr;
    zv2 += (k & 4)  ? -pr : pr;
    zv3 += (k & 2)  ? -pr : pr;
    zv4 += (k & 1)  ? -pr : pr;
    z5  += pr.x - pr.y;
  }
  const float P  = Pv.x + Pv.y;
  const float z0 = zv0.x + zv0.y, z1 = zv1.x + zv1.y, z2 = zv2.x + zv2.y;
  const float z3 = zv3.x + zv3.y, z4 = zv4.x + zv4.y;

  // ---- layer-2 angles (FULL angle): <Z>_final = ct*Z - st*X (R15/R16) ----
  float ct[12], sn[12];
#pragma unroll
  for (int q = 0; q < 12; ++q) {
    float th = ldv(w, NQ + q, f32);
    ct[q] = __cosf(th); sn[q] = __sinf(th);
  }
  const float zA[6] = {z0, z1, z2, z3, z4, z5};
  const float xA[6] = {xA0, xA1, xA2, xA3, xA4, xA5};
  const float xB[6] = {xB6, xB7, xB8, xB9, xB10, xB11};

  // ---- fused linear head (R16-verbatim) ----
  float t0, t1;
#pragma unroll
  for (int r = 0; r < 2; ++r) {
    float acc = 0.f, wsum = 0.f;
#pragma unroll
    for (int q = 0; q < 6; ++q) {
      float wv = ldv(Wm, r * NQ + q, f32);
      acc = fmaf(wv, fmaf(ct[q], zA[q], -sn[q] * xA[q]), acc);
    }
#pragma unroll
    for (int q = 6; q < 12; ++q) {
      float wv = ldv(Wm, r * NQ + q, f32);
      float wc = wv * ct[q];
      wsum += ((lane >> (11 - q)) & 1) ? -wc : wc;
      acc = fmaf(-wv * sn[q], xB[q - 6], acc);
    }
    acc = fmaf(P, wsum, acc);
    if (r == 0) t0 = acc; else t1 = acc;
  }
#pragma unroll
  for (int off = 32; off; off >>= 1) {
    t0 += __shfl_xor(t0, off, 64);
    t1 += __shfl_xor(t1, off, 64);
  }
  if (lane < 2) {
    float o = ((lane == 0) ? t0 : t1) + ldv(bv, lane, f32);
    if (f32) ((float*)out)[b * 2 + lane] = o;
    else     ((bf16*)out)[b * 2 + lane] = __float2bfloat16(o);
  }
}

extern "C" void kernel_launch(void* const* d_in, const int* in_sizes, int n_in,
                              void* d_out, int out_size, void* d_ws, size_t ws_size,
                              hipStream_t stream) {
  const void* x  = d_in[0];
  const void* w  = d_in[1];
  const void* Wm = d_in[2];
  const void* bv = d_in[3];
  const int batch = out_size / 2;   // out is [B, 2]
  qsim_kernel<<<dim3(batch), dim3(64), 0, stream>>>(x, w, Wm, bv, d_out);
}